// Round 11
// baseline (309.320 us; speedup 1.0000x reference)
//
#include <hip/hip_runtime.h>
#include <hip/hip_fp16.h>
#include <math.h>

#define DIM 128
#define KH 4

typedef unsigned int uint;
typedef unsigned short ushort;
using short8v = __attribute__((ext_vector_type(8))) short;
using f32x4 = __attribute__((ext_vector_type(4))) float;

// fp32 -> bf16 round-to-nearest-even
__device__ __forceinline__ uint f2bf(float f) {
  uint u = __float_as_uint(f);
  return (u + 0x7fffu + ((u >> 16) & 1u)) >> 16;
}
__device__ __forceinline__ float bf2f(uint u) { return __uint_as_float(u << 16); }
__device__ __forceinline__ float bflo(uint u) { return __uint_as_float(u << 16); }
__device__ __forceinline__ float bfhi(uint u) { return __uint_as_float(u & 0xffff0000u); }

// ---------------- init: x -> bf16 hi/lo split; packed per-(dst,k) degree count ----------------
__global__ __launch_bounds__(256) void k_init_count(
    const float4* __restrict__ xin,
    uint* __restrict__ Xhi, uint* __restrict__ Xlo,
    const int* __restrict__ ei, const int* __restrict__ attr,
    uint* __restrict__ degpack, int n4, int E) {
  int i = blockIdx.x * 256 + threadIdx.x;
  if (i < n4) {
    float4 v = xin[i];
    uint h0 = f2bf(v.x), h1 = f2bf(v.y), h2 = f2bf(v.z), h3 = f2bf(v.w);
    Xhi[i * 2 + 0] = h0 | (h1 << 16);
    Xhi[i * 2 + 1] = h2 | (h3 << 16);
    uint l0 = f2bf(v.x - bf2f(h0)), l1 = f2bf(v.y - bf2f(h1));
    uint l2 = f2bf(v.z - bf2f(h2)), l3 = f2bf(v.w - bf2f(h3));
    Xlo[i * 2 + 0] = l0 | (l1 << 16);
    Xlo[i * 2 + 1] = l2 | (l3 << 16);
  }
  if (i < E) {
    int dst = ei[E + i];
    int k = attr[i] - 1;
    atomicAdd(&degpack[dst], 1u << (k * 8));
  }
}

// ---------------- exclusive scan over per-node totals ----------------
__global__ __launch_bounds__(256) void k_scan1(const uint* __restrict__ degpack,
                                               int* __restrict__ off,
                                               int* __restrict__ bsum, int n) {
  __shared__ int s[256];
  int t = threadIdx.x;
  int i = blockIdx.x * 256 + t;
  int v = 0;
  if (i < n) {
    uint w = degpack[i];
    v = (w & 0xff) + ((w >> 8) & 0xff) + ((w >> 16) & 0xff) + (w >> 24);
  }
  s[t] = v;
  __syncthreads();
  for (int d = 1; d < 256; d <<= 1) {
    int u = (t >= d) ? s[t - d] : 0;
    __syncthreads();
    s[t] += u;
    __syncthreads();
  }
  if (i < n) off[i] = s[t] - v;
  if (t == 255) bsum[blockIdx.x] = s[255];
}

__global__ __launch_bounds__(256) void k_scan2(const int* __restrict__ bsum,
                                               int* __restrict__ bex, int nb) {
  __shared__ int s[256];
  int t = threadIdx.x;
  int v = (t < nb) ? bsum[t] : 0;
  s[t] = v;
  __syncthreads();
  for (int d = 1; d < 256; d <<= 1) {
    int u = (t >= d) ? s[t - d] : 0;
    __syncthreads();
    s[t] += u;
    __syncthreads();
  }
  if (t < nb) bex[t] = s[t] - v;
}

// finalize offsets + cursors + dinv; also W hi/lo split (merged one-shot work)
__global__ __launch_bounds__(256) void k_scan3w(int* __restrict__ off,
                                                const int* __restrict__ bex,
                                                const uint* __restrict__ degpack,
                                                int* __restrict__ cursor4,
                                                float* __restrict__ dinv, int n,
                                                const float* __restrict__ W,
                                                short* __restrict__ Whi,
                                                short* __restrict__ Wlo, int wtot) {
  int i = blockIdx.x * 256 + threadIdx.x;
  if (i < n) {
    int o = off[i] + bex[blockIdx.x];
    off[i] = o;
    uint w = degpack[i];
    int b0 = w & 0xff, b1 = (w >> 8) & 0xff, b2 = (w >> 16) & 0xff, b3 = w >> 24;
    int4 c;
    c.x = o;
    c.y = o + b0;
    c.z = o + b0 + b1;
    c.w = o + b0 + b1 + b2;
    *(int4*)&cursor4[i * 4] = c;
    float4 dv;
    dv.x = rsqrtf((float)b0 + 1.0f);
    dv.y = rsqrtf((float)b1 + 1.0f);
    dv.z = rsqrtf((float)b2 + 1.0f);
    dv.w = rsqrtf((float)b3 + 1.0f);
    *(float4*)&dinv[i * 4] = dv;
  }
  if (i < wtot) {
    int l = i >> 14;
    int rem = i & 16383;
    int k = rem >> 7;
    int ncol = rem & 127;
    float w = W[i];
    uint h = f2bf(w);
    uint lo = f2bf(w - bf2f(h));
    size_t o = (size_t)l * 16384 + (size_t)ncol * 128 + k;   // [layer][col][k]
    Whi[o] = (short)h;
    Wlo[o] = (short)lo;
  }
}

// ---------------- scatter: one 4B payload per edge, k-sorted within dst ----------------
__global__ __launch_bounds__(256) void k_scatter(const int* __restrict__ ei,
                                                 const int* __restrict__ attr,
                                                 const float* __restrict__ dinv,
                                                 int* __restrict__ cursor4,
                                                 uint* __restrict__ srcnm, int E) {
  int e = blockIdx.x * 256 + threadIdx.x;
  if (e >= E) return;
  int src = ei[e];
  int dst = ei[E + e];
  int k = attr[e] - 1;
  float nm = dinv[src * KH + k] * dinv[dst * KH + k];
  ushort h = __half_as_ushort(__float2half(nm));
  int pos = atomicAdd(&cursor4[dst * KH + k], 1);
  srcnm[pos] = (uint)src | ((uint)h << 16);
}

// ---------------- GEMM via 2-term split-bf16 MFMA: H = Xhi @ (Whi + Wlo), bf16 out ----------------
// H is stored bf16 anyway; dropping the Xlo*Whi term adds only ~1.4x the existing
// bf16 storage rounding. Residual precision is preserved separately (Xhi+Xlo in k_agg).
__global__ __launch_bounds__(512) void k_gemm(const uint* __restrict__ Xhi,
                                              const short* __restrict__ Whi, // [col][k]
                                              const short* __restrict__ Wlo,
                                              ushort* __restrict__ Hb16, int N) {
  __shared__ __align__(16) short xs_hi[64 * 128];
  int t = threadIdx.x;
  int r0 = blockIdx.x * 64;

  {
    int fi = t * 2;                  // 1024 half-loads done as 512 x 2
    int row = fi >> 4;
    int kq = fi & 15;
    int rg = r0 + row;
    if (rg >= N) rg = N - 1;
    int swz0 = kq ^ (row & 7);
    int swz1 = (kq + 1) ^ (row & 7);
    *(uint4*)&xs_hi[row * 128 + swz0 * 8] = *(const uint4*)&Xhi[(size_t)rg * 64 + kq * 4];
    *(uint4*)&xs_hi[row * 128 + swz1 * 8] = *(const uint4*)&Xhi[(size_t)rg * 64 + (kq + 1) * 4];
  }
  __syncthreads();

  int wid = t >> 6, lane = t & 63;
  int wrow = wid & 1, wcol = wid >> 1;   // 2 x 4 waves
  int lr = lane & 15, lk = lane >> 4;

  f32x4 acc[2][2];
#pragma unroll
  for (int a = 0; a < 2; ++a)
#pragma unroll
    for (int c = 0; c < 2; ++c) acc[a][c] = (f32x4){0.f, 0.f, 0.f, 0.f};

#pragma unroll
  for (int ks = 0; ks < 4; ++ks) {
    int k0 = ks * 32 + lk * 8;
    short8v ah[2];
#pragma unroll
    for (int rt = 0; rt < 2; ++rt) {
      int r = wrow * 32 + rt * 16 + lr;
      int slot = (k0 >> 3) ^ (r & 7);
      ah[rt] = *(short8v*)&xs_hi[r * 128 + slot * 8];
    }
    short8v bh[2], bl[2];
#pragma unroll
    for (int ct = 0; ct < 2; ++ct) {
      int col = wcol * 32 + ct * 16 + lr;
      bh[ct] = *(const short8v*)&Whi[(size_t)col * 128 + k0];
      bl[ct] = *(const short8v*)&Wlo[(size_t)col * 128 + k0];
    }
#pragma unroll
    for (int rt = 0; rt < 2; ++rt)
#pragma unroll
      for (int ct = 0; ct < 2; ++ct) {
        acc[rt][ct] = __builtin_amdgcn_mfma_f32_16x16x32_bf16(ah[rt], bh[ct], acc[rt][ct], 0, 0, 0);
        acc[rt][ct] = __builtin_amdgcn_mfma_f32_16x16x32_bf16(ah[rt], bl[ct], acc[rt][ct], 0, 0, 0);
      }
  }

#pragma unroll
  for (int rt = 0; rt < 2; ++rt)
#pragma unroll
    for (int ct = 0; ct < 2; ++ct) {
      int col = wcol * 32 + ct * 16 + lr;
#pragma unroll
      for (int i = 0; i < 4; ++i) {
        int row = r0 + wrow * 32 + rt * 16 + lk * 4 + i;
        if (row < N) Hb16[(size_t)row * 128 + col] = (ushort)f2bf(acc[rt][ct][i]);
      }
    }
}

// ---------------- aggregate + self-loop + bias + residual ReLU + L2 norm ----------------
// 1 wave/node. Gather: uint4 per lane, 16 lanes/row, 4 edges per wave-load (requests /4).
__global__ __launch_bounds__(256) void k_agg(const int* __restrict__ off,
                                             const uint* __restrict__ degpack,
                                             const uint* __restrict__ srcnm,
                                             const float* __restrict__ dinv,
                                             const uint* __restrict__ Hb,
                                             const float* __restrict__ bias,
                                             const float* __restrict__ alpha,
                                             uint* __restrict__ Xhi,
                                             uint* __restrict__ Xlo,
                                             float2* __restrict__ Xout,
                                             int last, int N) {
  int wid = threadIdx.x >> 6;
  int lane = threadIdx.x & 63;
  int n = blockIdx.x * 4 + wid;
  if (n >= N) return;

  float a0 = alpha[0], a1 = alpha[1], a2 = alpha[2], a3 = alpha[3];
  float m = fmaxf(fmaxf(a0, a1), fmaxf(a2, a3));
  a0 = __expf(a0 - m); a1 = __expf(a1 - m); a2 = __expf(a2 - m); a3 = __expf(a3 - m);
  float is = 1.0f / (a0 + a1 + a2 + a3);
  a0 *= is; a1 *= is; a2 *= is; a3 *= is;

  uint w = degpack[n];
  int b0 = w & 0xff, b1 = (w >> 8) & 0xff, b2 = (w >> 16) & 0xff, b3 = (int)(w >> 24);
  int e0 = off[n];
  int e1 = e0 + b0 + b1 + b2 + b3;
  int k1 = e0 + b0, k2 = k1 + b1, k3 = k2 + b2;

  int g = lane >> 4;       // edge group 0..3
  int cl = lane & 15;      // uint4 slot within row
  const uint4* Hb4 = (const uint4*)Hb;

  float ax0 = 0.f, ax1 = 0.f, ax2 = 0.f, ax3 = 0.f;
  float ay0 = 0.f, ay1 = 0.f, ay2 = 0.f, ay3 = 0.f;

  for (int base = e0; base < e1; base += 64) {
    int cnt = min(64, e1 - base);
    int sofs = 0;        // src * 16 (uint4 row offset)
    float wc = 0.f;
    if (lane < cnt) {
      uint v = srcnm[base + lane];
      int pos = base + lane;
      int k = (pos >= k1) + (pos >= k2) + (pos >= k3);
      float ak = (k == 0) ? a0 : (k == 1) ? a1 : (k == 2) ? a2 : a3;
      wc = ak * __half2float(__ushort_as_half((ushort)(v >> 16)));
      sofs = (int)(v & 0xFFFFu) << 4;
    }
    int j = 0;
    for (; j + 8 <= cnt; j += 8) {
      int i0 = j + g, i1 = j + 4 + g;
      int s0 = __shfl(sofs, i0);
      int s1 = __shfl(sofs, i1);
      float w0 = __shfl(wc, i0);
      float w1 = __shfl(wc, i1);
      uint4 u0 = Hb4[s0 + cl];
      uint4 u1 = Hb4[s1 + cl];
      ax0 = fmaf(w0, bflo(u0.x), ax0); ay0 = fmaf(w0, bfhi(u0.x), ay0);
      ax1 = fmaf(w0, bflo(u0.y), ax1); ay1 = fmaf(w0, bfhi(u0.y), ay1);
      ax2 = fmaf(w0, bflo(u0.z), ax2); ay2 = fmaf(w0, bfhi(u0.z), ay2);
      ax3 = fmaf(w0, bflo(u0.w), ax3); ay3 = fmaf(w0, bfhi(u0.w), ay3);
      ax0 = fmaf(w1, bflo(u1.x), ax0); ay0 = fmaf(w1, bfhi(u1.x), ay0);
      ax1 = fmaf(w1, bflo(u1.y), ax1); ay1 = fmaf(w1, bfhi(u1.y), ay1);
      ax2 = fmaf(w1, bflo(u1.z), ax2); ay2 = fmaf(w1, bfhi(u1.z), ay2);
      ax3 = fmaf(w1, bflo(u1.w), ax3); ay3 = fmaf(w1, bfhi(u1.w), ay3);
    }
    for (; j < cnt; j += 4) {
      int i0 = j + g;                      // lanes past cnt carry wc=0
      int s0 = __shfl(sofs, i0);
      float w0 = __shfl(wc, i0);
      uint4 u0 = Hb4[s0 + cl];
      ax0 = fmaf(w0, bflo(u0.x), ax0); ay0 = fmaf(w0, bfhi(u0.x), ay0);
      ax1 = fmaf(w0, bflo(u0.y), ax1); ay1 = fmaf(w0, bfhi(u0.y), ay1);
      ax2 = fmaf(w0, bflo(u0.z), ax2); ay2 = fmaf(w0, bfhi(u0.z), ay2);
      ax3 = fmaf(w0, bflo(u0.w), ax3); ay3 = fmaf(w0, bfhi(u0.w), ay3);
    }
  }

  // reduce across the 4 edge-groups (lanes cl, cl+16, cl+32, cl+48)
  ax0 += __shfl_xor(ax0, 16); ax0 += __shfl_xor(ax0, 32);
  ax1 += __shfl_xor(ax1, 16); ax1 += __shfl_xor(ax1, 32);
  ax2 += __shfl_xor(ax2, 16); ax2 += __shfl_xor(ax2, 32);
  ax3 += __shfl_xor(ax3, 16); ax3 += __shfl_xor(ax3, 32);
  ay0 += __shfl_xor(ay0, 16); ay0 += __shfl_xor(ay0, 32);
  ay1 += __shfl_xor(ay1, 16); ay1 += __shfl_xor(ay1, 32);
  ay2 += __shfl_xor(ay2, 16); ay2 += __shfl_xor(ay2, 32);
  ay3 += __shfl_xor(ay3, 16); ay3 += __shfl_xor(ay3, 32);

  // lane takes component g of slot cl -> owns uint q (cols 2q, 2q+1); q is a lane bijection
  int q = cl * 4 + g;
  float accx = (g == 0) ? ax0 : (g == 1) ? ax1 : (g == 2) ? ax2 : ax3;
  float accy = (g == 0) ? ay0 : (g == 1) ? ay1 : (g == 2) ? ay2 : ay3;

  // self-loop coefficient: sum_k a_k * dinv^2
  float4 dv = *(const float4*)&dinv[n * 4];
  float sc = a0 * dv.x * dv.x + a1 * dv.y * dv.y + a2 * dv.z * dv.z + a3 * dv.w * dv.w;

  uint un = Hb[(size_t)n * 64 + q];
  float2 bb = ((const float2*)bias)[q];
  uint xh = Xhi[(size_t)n * 64 + q];
  uint xl = Xlo[(size_t)n * 64 + q];
  float xr0 = bf2f(xh) + bf2f(xl);                  // ~fp32 residual base
  float xr1 = bfhi(xh) + bfhi(xl);
  float o0 = accx + sc * bflo(un) + bb.x;
  float o1 = accy + sc * bfhi(un) + bb.y;
  float x0 = xr0 + fmaxf(o0, 0.f);
  float x1 = xr1 + fmaxf(o1, 0.f);

  float ss = x0 * x0 + x1 * x1;
#pragma unroll
  for (int d = 32; d; d >>= 1) ss += __shfl_xor(ss, d);
  float nrm = fmaxf(sqrtf(ss), 1e-12f);
  float inv = 1.0f / nrm;
  float y0 = x0 * inv, y1 = x1 * inv;

  uint h0 = f2bf(y0), h1 = f2bf(y1);
  Xhi[(size_t)n * 64 + q] = h0 | (h1 << 16);
  uint l0 = f2bf(y0 - bf2f(h0)), l1 = f2bf(y1 - bf2f(h1));
  Xlo[(size_t)n * 64 + q] = l0 | (l1 << 16);
  if (last) Xout[(size_t)n * 64 + q] = make_float2(y0, y1);
}

// ---------------- host launcher ----------------
extern "C" void kernel_launch(void* const* d_in, const int* in_sizes, int n_in,
                              void* d_out, int out_size, void* d_ws, size_t ws_size,
                              hipStream_t stream) {
  const float* x = (const float*)d_in[0];
  const int* ei = (const int*)d_in[1];
  const int* attr = (const int*)d_in[2];
  const float* W = (const float*)d_in[3];
  const float* b = (const float*)d_in[4];
  const float* alpha = (const float*)d_in[5];
  float* X = (float*)d_out;

  int N = in_sizes[0] / DIM;
  int E = in_sizes[1] / 2;
  int L = in_sizes[3] / (DIM * DIM);

  char* base = (char*)d_ws;
  size_t ofs = 0;
  auto carve = [&](size_t bytes) -> void* {
    void* p = base + ofs;
    ofs = (ofs + bytes + 255) & ~(size_t)255;
    return p;
  };
  int* off = (int*)carve((size_t)(N + 1) * 4);
  int* cursor4 = (int*)carve((size_t)N * KH * 4);
  uint* degpack = (uint*)carve((size_t)N * 4);
  float* dinv = (float*)carve((size_t)N * KH * 4);
  int* bsum = (int*)carve(256 * 4);
  int* bex = (int*)carve(256 * 4);
  uint* srcnm = (uint*)carve((size_t)E * 4);
  uint* Hb = (uint*)carve((size_t)N * 64 * 4);
  uint* Xhi = (uint*)carve((size_t)N * 64 * 4);
  uint* Xlo = (uint*)carve((size_t)N * 64 * 4);
  short* Whi = (short*)carve((size_t)L * DIM * DIM * 2);
  short* Wlo = (short*)carve((size_t)L * DIM * DIM * 2);

  int n4 = N * DIM / 4;
  int nb = (N + 255) / 256;
  int wtot = L * DIM * DIM;
  int gmax = (wtot > N) ? wtot : N;
  int imax = (n4 > E) ? n4 : E;

  hipMemsetAsync(degpack, 0, (size_t)N * 4, stream);
  k_init_count<<<(imax + 255) / 256, 256, 0, stream>>>((const float4*)x, Xhi, Xlo,
                                                       ei, attr, degpack, n4, E);
  k_scan1<<<nb, 256, 0, stream>>>(degpack, off, bsum, N);
  k_scan2<<<1, 256, 0, stream>>>(bsum, bex, nb);
  k_scan3w<<<(gmax + 255) / 256, 256, 0, stream>>>(off, bex, degpack, cursor4, dinv, N,
                                                   W, Whi, Wlo, wtot);
  k_scatter<<<(E + 255) / 256, 256, 0, stream>>>(ei, attr, dinv, cursor4, srcnm, E);

  for (int t = 0; t < L; ++t) {
    k_gemm<<<(N + 63) / 64, 512, 0, stream>>>(Xhi,
                                              Whi + (size_t)t * DIM * DIM,
                                              Wlo + (size_t)t * DIM * DIM,
                                              (ushort*)Hb, N);
    k_agg<<<(N + 3) / 4, 256, 0, stream>>>(off, degpack, srcnm, dinv, Hb,
                                           b + (size_t)t * DIM, alpha + (size_t)t * KH,
                                           Xhi, Xlo, (float2*)X,
                                           (t == L - 1) ? 1 : 0, N);
  }
}

// Round 12
// 305.765 us; speedup vs baseline: 1.0116x; 1.0116x over previous
//
#include <hip/hip_runtime.h>
#include <hip/hip_fp16.h>
#include <math.h>

#define DIM 128
#define KH 4

typedef unsigned int uint;
typedef unsigned short ushort;
using short8v = __attribute__((ext_vector_type(8))) short;
using f32x4 = __attribute__((ext_vector_type(4))) float;

// fp32 -> bf16 round-to-nearest-even
__device__ __forceinline__ uint f2bf(float f) {
  uint u = __float_as_uint(f);
  return (u + 0x7fffu + ((u >> 16) & 1u)) >> 16;
}
__device__ __forceinline__ float bf2f(uint u) { return __uint_as_float(u << 16); }
__device__ __forceinline__ float bflo(uint u) { return __uint_as_float(u << 16); }
__device__ __forceinline__ float bfhi(uint u) { return __uint_as_float(u & 0xffff0000u); }

// ---------------- zero degpack (replaces pathological rocclr fill) ----------------
__global__ __launch_bounds__(256) void k_zero(uint* __restrict__ p, int n) {
  int i = blockIdx.x * 256 + threadIdx.x;
  if (i < n) p[i] = 0u;
}

// ---------------- init: x -> bf16 hi/lo split; packed per-(dst,k) degree count ----------------
__global__ __launch_bounds__(256) void k_init_count(
    const float4* __restrict__ xin,
    uint* __restrict__ Xhi, uint* __restrict__ Xlo,
    const int* __restrict__ ei, const int* __restrict__ attr,
    uint* __restrict__ degpack, int n4, int E) {
  int i = blockIdx.x * 256 + threadIdx.x;
  if (i < n4) {
    float4 v = xin[i];
    uint h0 = f2bf(v.x), h1 = f2bf(v.y), h2 = f2bf(v.z), h3 = f2bf(v.w);
    Xhi[i * 2 + 0] = h0 | (h1 << 16);
    Xhi[i * 2 + 1] = h2 | (h3 << 16);
    uint l0 = f2bf(v.x - bf2f(h0)), l1 = f2bf(v.y - bf2f(h1));
    uint l2 = f2bf(v.z - bf2f(h2)), l3 = f2bf(v.w - bf2f(h3));
    Xlo[i * 2 + 0] = l0 | (l1 << 16);
    Xlo[i * 2 + 1] = l2 | (l3 << 16);
  }
  if (i < E) {
    int dst = ei[E + i];
    int k = attr[i] - 1;
    atomicAdd(&degpack[dst], 1u << (k * 8));
  }
}

// ---------------- exclusive scan over per-node totals ----------------
__global__ __launch_bounds__(256) void k_scan1(const uint* __restrict__ degpack,
                                               int* __restrict__ off,
                                               int* __restrict__ bsum, int n) {
  __shared__ int s[256];
  int t = threadIdx.x;
  int i = blockIdx.x * 256 + t;
  int v = 0;
  if (i < n) {
    uint w = degpack[i];
    v = (w & 0xff) + ((w >> 8) & 0xff) + ((w >> 16) & 0xff) + (w >> 24);
  }
  s[t] = v;
  __syncthreads();
  for (int d = 1; d < 256; d <<= 1) {
    int u = (t >= d) ? s[t - d] : 0;
    __syncthreads();
    s[t] += u;
    __syncthreads();
  }
  if (i < n) off[i] = s[t] - v;
  if (t == 255) bsum[blockIdx.x] = s[255];
}

__global__ __launch_bounds__(256) void k_scan2(const int* __restrict__ bsum,
                                               int* __restrict__ bex, int nb) {
  __shared__ int s[256];
  int t = threadIdx.x;
  int v = (t < nb) ? bsum[t] : 0;
  s[t] = v;
  __syncthreads();
  for (int d = 1; d < 256; d <<= 1) {
    int u = (t >= d) ? s[t - d] : 0;
    __syncthreads();
    s[t] += u;
    __syncthreads();
  }
  if (t < nb) bex[t] = s[t] - v;
}

// finalize offsets + cursors + dinv; also W hi/lo split (merged one-shot work)
__global__ __launch_bounds__(256) void k_scan3w(int* __restrict__ off,
                                                const int* __restrict__ bex,
                                                const uint* __restrict__ degpack,
                                                int* __restrict__ cursor4,
                                                float* __restrict__ dinv, int n,
                                                const float* __restrict__ W,
                                                short* __restrict__ Whi,
                                                short* __restrict__ Wlo, int wtot) {
  int i = blockIdx.x * 256 + threadIdx.x;
  if (i < n) {
    int o = off[i] + bex[blockIdx.x];
    off[i] = o;
    uint w = degpack[i];
    int b0 = w & 0xff, b1 = (w >> 8) & 0xff, b2 = (w >> 16) & 0xff, b3 = w >> 24;
    int4 c;
    c.x = o;
    c.y = o + b0;
    c.z = o + b0 + b1;
    c.w = o + b0 + b1 + b2;
    *(int4*)&cursor4[i * 4] = c;
    float4 dv;
    dv.x = rsqrtf((float)b0 + 1.0f);
    dv.y = rsqrtf((float)b1 + 1.0f);
    dv.z = rsqrtf((float)b2 + 1.0f);
    dv.w = rsqrtf((float)b3 + 1.0f);
    *(float4*)&dinv[i * 4] = dv;
  }
  if (i < wtot) {
    int l = i >> 14;
    int rem = i & 16383;
    int k = rem >> 7;
    int ncol = rem & 127;
    float w = W[i];
    uint h = f2bf(w);
    uint lo = f2bf(w - bf2f(h));
    size_t o = (size_t)l * 16384 + (size_t)ncol * 128 + k;   // [layer][col][k]
    Whi[o] = (short)h;
    Wlo[o] = (short)lo;
  }
}

// ---------------- scatter: one 4B payload per edge, k-sorted within dst ----------------
__global__ __launch_bounds__(256) void k_scatter(const int* __restrict__ ei,
                                                 const int* __restrict__ attr,
                                                 const float* __restrict__ dinv,
                                                 int* __restrict__ cursor4,
                                                 uint* __restrict__ srcnm, int E) {
  int e = blockIdx.x * 256 + threadIdx.x;
  if (e >= E) return;
  int src = ei[e];
  int dst = ei[E + e];
  int k = attr[e] - 1;
  float nm = dinv[src * KH + k] * dinv[dst * KH + k];
  ushort h = __half_as_ushort(__float2half(nm));
  int pos = atomicAdd(&cursor4[dst * KH + k], 1);
  srcnm[pos] = (uint)src | ((uint)h << 16);
}

// ---------------- GEMM via 2-term split-bf16 MFMA: H = Xhi @ (Whi + Wlo), bf16 out ----------------
__global__ __launch_bounds__(512) void k_gemm(const uint* __restrict__ Xhi,
                                              const short* __restrict__ Whi, // [col][k]
                                              const short* __restrict__ Wlo,
                                              ushort* __restrict__ Hb16, int N) {
  __shared__ __align__(16) short xs_hi[64 * 128];
  int t = threadIdx.x;
  int r0 = blockIdx.x * 64;

  {
    int fi = t * 2;                  // 1024 half-loads done as 512 x 2
    int row = fi >> 4;
    int kq = fi & 15;
    int rg = r0 + row;
    if (rg >= N) rg = N - 1;
    int swz0 = kq ^ (row & 7);
    int swz1 = (kq + 1) ^ (row & 7);
    *(uint4*)&xs_hi[row * 128 + swz0 * 8] = *(const uint4*)&Xhi[(size_t)rg * 64 + kq * 4];
    *(uint4*)&xs_hi[row * 128 + swz1 * 8] = *(const uint4*)&Xhi[(size_t)rg * 64 + (kq + 1) * 4];
  }
  __syncthreads();

  int wid = t >> 6, lane = t & 63;
  int wrow = wid & 1, wcol = wid >> 1;   // 2 x 4 waves
  int lr = lane & 15, lk = lane >> 4;

  f32x4 acc[2][2];
#pragma unroll
  for (int a = 0; a < 2; ++a)
#pragma unroll
    for (int c = 0; c < 2; ++c) acc[a][c] = (f32x4){0.f, 0.f, 0.f, 0.f};

#pragma unroll
  for (int ks = 0; ks < 4; ++ks) {
    int k0 = ks * 32 + lk * 8;
    short8v ah[2];
#pragma unroll
    for (int rt = 0; rt < 2; ++rt) {
      int r = wrow * 32 + rt * 16 + lr;
      int slot = (k0 >> 3) ^ (r & 7);
      ah[rt] = *(short8v*)&xs_hi[r * 128 + slot * 8];
    }
    short8v bh[2], bl[2];
#pragma unroll
    for (int ct = 0; ct < 2; ++ct) {
      int col = wcol * 32 + ct * 16 + lr;
      bh[ct] = *(const short8v*)&Whi[(size_t)col * 128 + k0];
      bl[ct] = *(const short8v*)&Wlo[(size_t)col * 128 + k0];
    }
#pragma unroll
    for (int rt = 0; rt < 2; ++rt)
#pragma unroll
      for (int ct = 0; ct < 2; ++ct) {
        acc[rt][ct] = __builtin_amdgcn_mfma_f32_16x16x32_bf16(ah[rt], bh[ct], acc[rt][ct], 0, 0, 0);
        acc[rt][ct] = __builtin_amdgcn_mfma_f32_16x16x32_bf16(ah[rt], bl[ct], acc[rt][ct], 0, 0, 0);
      }
  }

#pragma unroll
  for (int rt = 0; rt < 2; ++rt)
#pragma unroll
    for (int ct = 0; ct < 2; ++ct) {
      int col = wcol * 32 + ct * 16 + lr;
#pragma unroll
      for (int i = 0; i < 4; ++i) {
        int row = r0 + wrow * 32 + rt * 16 + lk * 4 + i;
        if (row < N) Hb16[(size_t)row * 128 + col] = (ushort)f2bf(acc[rt][ct][i]);
      }
    }
}

// ---------------- aggregate + self-loop + bias + residual ReLU + L2 norm ----------------
// 1 wave/node; uint4 x 16-lane rows (4 edges/wave-load); epilogue loads hoisted
// above the gather loop so their latency overlaps the gather chain.
__global__ __launch_bounds__(256) void k_agg(const int* __restrict__ off,
                                             const uint* __restrict__ degpack,
                                             const uint* __restrict__ srcnm,
                                             const float* __restrict__ dinv,
                                             const uint* __restrict__ Hb,
                                             const float* __restrict__ bias,
                                             const float* __restrict__ alpha,
                                             uint* __restrict__ Xhi,
                                             uint* __restrict__ Xlo,
                                             float2* __restrict__ Xout,
                                             int last, int N) {
  int wid = threadIdx.x >> 6;
  int lane = threadIdx.x & 63;
  int n = blockIdx.x * 4 + wid;
  if (n >= N) return;

  int g = lane >> 4;       // edge group 0..3
  int cl = lane & 15;      // uint4 slot within row
  int q = cl * 4 + g;      // lane's owned uint column (bijection)

  // ---- hoisted epilogue loads (independent of the gather) ----
  uint un = Hb[(size_t)n * 64 + q];
  float2 bb = ((const float2*)bias)[q];
  uint xh = Xhi[(size_t)n * 64 + q];
  uint xl = Xlo[(size_t)n * 64 + q];
  float4 dv = *(const float4*)&dinv[n * 4];

  float a0 = alpha[0], a1 = alpha[1], a2 = alpha[2], a3 = alpha[3];
  float m = fmaxf(fmaxf(a0, a1), fmaxf(a2, a3));
  a0 = __expf(a0 - m); a1 = __expf(a1 - m); a2 = __expf(a2 - m); a3 = __expf(a3 - m);
  float is = 1.0f / (a0 + a1 + a2 + a3);
  a0 *= is; a1 *= is; a2 *= is; a3 *= is;

  uint w = degpack[n];
  int b0 = w & 0xff, b1 = (w >> 8) & 0xff, b2 = (w >> 16) & 0xff, b3 = (int)(w >> 24);
  int e0 = off[n];
  int e1 = e0 + b0 + b1 + b2 + b3;
  int k1 = e0 + b0, k2 = k1 + b1, k3 = k2 + b2;

  const uint4* Hb4 = (const uint4*)Hb;

  float ax0 = 0.f, ax1 = 0.f, ax2 = 0.f, ax3 = 0.f;
  float ay0 = 0.f, ay1 = 0.f, ay2 = 0.f, ay3 = 0.f;

  for (int base = e0; base < e1; base += 64) {
    int cnt = min(64, e1 - base);
    int sofs = 0;        // src * 16 (uint4 row offset)
    float wc = 0.f;
    if (lane < cnt) {
      uint v = srcnm[base + lane];
      int pos = base + lane;
      int k = (pos >= k1) + (pos >= k2) + (pos >= k3);
      float ak = (k == 0) ? a0 : (k == 1) ? a1 : (k == 2) ? a2 : a3;
      wc = ak * __half2float(__ushort_as_half((ushort)(v >> 16)));
      sofs = (int)(v & 0xFFFFu) << 4;
    }
    int j = 0;
    for (; j + 8 <= cnt; j += 8) {
      int i0 = j + g, i1 = j + 4 + g;
      int s0 = __shfl(sofs, i0);
      int s1 = __shfl(sofs, i1);
      float w0 = __shfl(wc, i0);
      float w1 = __shfl(wc, i1);
      uint4 u0 = Hb4[s0 + cl];
      uint4 u1 = Hb4[s1 + cl];
      ax0 = fmaf(w0, bflo(u0.x), ax0); ay0 = fmaf(w0, bfhi(u0.x), ay0);
      ax1 = fmaf(w0, bflo(u0.y), ax1); ay1 = fmaf(w0, bfhi(u0.y), ay1);
      ax2 = fmaf(w0, bflo(u0.z), ax2); ay2 = fmaf(w0, bfhi(u0.z), ay2);
      ax3 = fmaf(w0, bflo(u0.w), ax3); ay3 = fmaf(w0, bfhi(u0.w), ay3);
      ax0 = fmaf(w1, bflo(u1.x), ax0); ay0 = fmaf(w1, bfhi(u1.x), ay0);
      ax1 = fmaf(w1, bflo(u1.y), ax1); ay1 = fmaf(w1, bfhi(u1.y), ay1);
      ax2 = fmaf(w1, bflo(u1.z), ax2); ay2 = fmaf(w1, bfhi(u1.z), ay2);
      ax3 = fmaf(w1, bflo(u1.w), ax3); ay3 = fmaf(w1, bfhi(u1.w), ay3);
    }
    for (; j < cnt; j += 4) {
      int i0 = j + g;                      // lanes past cnt carry wc=0
      int s0 = __shfl(sofs, i0);
      float w0 = __shfl(wc, i0);
      uint4 u0 = Hb4[s0 + cl];
      ax0 = fmaf(w0, bflo(u0.x), ax0); ay0 = fmaf(w0, bfhi(u0.x), ay0);
      ax1 = fmaf(w0, bflo(u0.y), ax1); ay1 = fmaf(w0, bfhi(u0.y), ay1);
      ax2 = fmaf(w0, bflo(u0.z), ax2); ay2 = fmaf(w0, bfhi(u0.z), ay2);
      ax3 = fmaf(w0, bflo(u0.w), ax3); ay3 = fmaf(w0, bfhi(u0.w), ay3);
    }
  }

  // reduce across the 4 edge-groups (lanes cl, cl+16, cl+32, cl+48)
  ax0 += __shfl_xor(ax0, 16); ax0 += __shfl_xor(ax0, 32);
  ax1 += __shfl_xor(ax1, 16); ax1 += __shfl_xor(ax1, 32);
  ax2 += __shfl_xor(ax2, 16); ax2 += __shfl_xor(ax2, 32);
  ax3 += __shfl_xor(ax3, 16); ax3 += __shfl_xor(ax3, 32);
  ay0 += __shfl_xor(ay0, 16); ay0 += __shfl_xor(ay0, 32);
  ay1 += __shfl_xor(ay1, 16); ay1 += __shfl_xor(ay1, 32);
  ay2 += __shfl_xor(ay2, 16); ay2 += __shfl_xor(ay2, 32);
  ay3 += __shfl_xor(ay3, 16); ay3 += __shfl_xor(ay3, 32);

  float accx = (g == 0) ? ax0 : (g == 1) ? ax1 : (g == 2) ? ax2 : ax3;
  float accy = (g == 0) ? ay0 : (g == 1) ? ay1 : (g == 2) ? ay2 : ay3;

  // self-loop coefficient: sum_k a_k * dinv^2
  float sc = a0 * dv.x * dv.x + a1 * dv.y * dv.y + a2 * dv.z * dv.z + a3 * dv.w * dv.w;

  float xr0 = bf2f(xh) + bf2f(xl);                  // ~fp32 residual base
  float xr1 = bfhi(xh) + bfhi(xl);
  float o0 = accx + sc * bflo(un) + bb.x;
  float o1 = accy + sc * bfhi(un) + bb.y;
  float x0 = xr0 + fmaxf(o0, 0.f);
  float x1 = xr1 + fmaxf(o1, 0.f);

  float ss = x0 * x0 + x1 * x1;
#pragma unroll
  for (int d = 32; d; d >>= 1) ss += __shfl_xor(ss, d);
  float nrm = fmaxf(sqrtf(ss), 1e-12f);
  float inv = 1.0f / nrm;
  float y0 = x0 * inv, y1 = x1 * inv;

  uint h0 = f2bf(y0), h1 = f2bf(y1);
  Xhi[(size_t)n * 64 + q] = h0 | (h1 << 16);
  uint l0 = f2bf(y0 - bf2f(h0)), l1 = f2bf(y1 - bf2f(h1));
  Xlo[(size_t)n * 64 + q] = l0 | (l1 << 16);
  if (last) Xout[(size_t)n * 64 + q] = make_float2(y0, y1);
}

// ---------------- host launcher ----------------
extern "C" void kernel_launch(void* const* d_in, const int* in_sizes, int n_in,
                              void* d_out, int out_size, void* d_ws, size_t ws_size,
                              hipStream_t stream) {
  const float* x = (const float*)d_in[0];
  const int* ei = (const int*)d_in[1];
  const int* attr = (const int*)d_in[2];
  const float* W = (const float*)d_in[3];
  const float* b = (const float*)d_in[4];
  const float* alpha = (const float*)d_in[5];
  float* X = (float*)d_out;

  int N = in_sizes[0] / DIM;
  int E = in_sizes[1] / 2;
  int L = in_sizes[3] / (DIM * DIM);

  char* base = (char*)d_ws;
  size_t ofs = 0;
  auto carve = [&](size_t bytes) -> void* {
    void* p = base + ofs;
    ofs = (ofs + bytes + 255) & ~(size_t)255;
    return p;
  };
  int* off = (int*)carve((size_t)(N + 1) * 4);
  int* cursor4 = (int*)carve((size_t)N * KH * 4);
  uint* degpack = (uint*)carve((size_t)N * 4);
  float* dinv = (float*)carve((size_t)N * KH * 4);
  int* bsum = (int*)carve(256 * 4);
  int* bex = (int*)carve(256 * 4);
  uint* srcnm = (uint*)carve((size_t)E * 4);
  uint* Hb = (uint*)carve((size_t)N * 64 * 4);
  uint* Xhi = (uint*)carve((size_t)N * 64 * 4);
  uint* Xlo = (uint*)carve((size_t)N * 64 * 4);
  short* Whi = (short*)carve((size_t)L * DIM * DIM * 2);
  short* Wlo = (short*)carve((size_t)L * DIM * DIM * 2);

  int n4 = N * DIM / 4;
  int nb = (N + 255) / 256;
  int wtot = L * DIM * DIM;
  int gmax = (wtot > N) ? wtot : N;
  int imax = (n4 > E) ? n4 : E;

  k_zero<<<(N + 255) / 256, 256, 0, stream>>>(degpack, N);
  k_init_count<<<(imax + 255) / 256, 256, 0, stream>>>((const float4*)x, Xhi, Xlo,
                                                       ei, attr, degpack, n4, E);
  k_scan1<<<nb, 256, 0, stream>>>(degpack, off, bsum, N);
  k_scan2<<<1, 256, 0, stream>>>(bsum, bex, nb);
  k_scan3w<<<(gmax + 255) / 256, 256, 0, stream>>>(off, bex, degpack, cursor4, dinv, N,
                                                   W, Whi, Wlo, wtot);
  k_scatter<<<(E + 255) / 256, 256, 0, stream>>>(ei, attr, dinv, cursor4, srcnm, E);

  for (int t = 0; t < L; ++t) {
    k_gemm<<<(N + 63) / 64, 512, 0, stream>>>(Xhi,
                                              Whi + (size_t)t * DIM * DIM,
                                              Wlo + (size_t)t * DIM * DIM,
                                              (ushort*)Hb, N);
    k_agg<<<(N + 3) / 4, 256, 0, stream>>>(off, degpack, srcnm, dinv, Hb,
                                           b + (size_t)t * DIM, alpha + (size_t)t * KH,
                                           Xhi, Xlo, (float2*)X,
                                           (t == L - 1) ? 1 : 0, N);
  }
}

// Round 13
// 295.120 us; speedup vs baseline: 1.0481x; 1.0361x over previous
//
#include <hip/hip_runtime.h>
#include <hip/hip_fp16.h>
#include <math.h>

#define DIM 128
#define KH 4

typedef unsigned int uint;
typedef unsigned short ushort;
using short8v = __attribute__((ext_vector_type(8))) short;
using f32x4 = __attribute__((ext_vector_type(4))) float;

// fp32 -> bf16 round-to-nearest-even
__device__ __forceinline__ uint f2bf(float f) {
  uint u = __float_as_uint(f);
  return (u + 0x7fffu + ((u >> 16) & 1u)) >> 16;
}
__device__ __forceinline__ float bf2f(uint u) { return __uint_as_float(u << 16); }
__device__ __forceinline__ float bflo(uint u) { return __uint_as_float(u << 16); }
__device__ __forceinline__ float bfhi(uint u) { return __uint_as_float(u & 0xffff0000u); }

// ---------------- zero degpack ----------------
__global__ __launch_bounds__(256) void k_zero(uint* __restrict__ p, int n) {
  int i = blockIdx.x * 256 + threadIdx.x;
  if (i < n) p[i] = 0u;
}

// ---------------- init: x -> bf16 hi/lo; degree count; W hi/lo split ----------------
__global__ __launch_bounds__(256) void k_init_count(
    const float4* __restrict__ xin,
    uint* __restrict__ Xhi, uint* __restrict__ Xlo,
    const int* __restrict__ ei, const int* __restrict__ attr,
    uint* __restrict__ degpack,
    const float* __restrict__ W,
    short* __restrict__ Whi, short* __restrict__ Wlo,
    int n4, int E, int wtot) {
  int i = blockIdx.x * 256 + threadIdx.x;
  if (i < n4) {
    float4 v = xin[i];
    uint h0 = f2bf(v.x), h1 = f2bf(v.y), h2 = f2bf(v.z), h3 = f2bf(v.w);
    Xhi[i * 2 + 0] = h0 | (h1 << 16);
    Xhi[i * 2 + 1] = h2 | (h3 << 16);
    uint l0 = f2bf(v.x - bf2f(h0)), l1 = f2bf(v.y - bf2f(h1));
    uint l2 = f2bf(v.z - bf2f(h2)), l3 = f2bf(v.w - bf2f(h3));
    Xlo[i * 2 + 0] = l0 | (l1 << 16);
    Xlo[i * 2 + 1] = l2 | (l3 << 16);
  }
  if (i < E) {
    int dst = ei[E + i];
    int k = attr[i] - 1;
    atomicAdd(&degpack[dst], 1u << (k * 8));
  }
  if (i < wtot) {
    int l = i >> 14;
    int rem = i & 16383;
    int k = rem >> 7;
    int ncol = rem & 127;
    float w = W[i];
    uint h = f2bf(w);
    uint lo = f2bf(w - bf2f(h));
    size_t o = (size_t)l * 16384 + (size_t)ncol * 128 + k;   // [layer][col][k]
    Whi[o] = (short)h;
    Wlo[o] = (short)lo;
  }
}

// ---------------- exclusive scan over per-node totals ----------------
__global__ __launch_bounds__(256) void k_scan1(const uint* __restrict__ degpack,
                                               int* __restrict__ off,
                                               int* __restrict__ bsum, int n) {
  __shared__ int s[256];
  int t = threadIdx.x;
  int i = blockIdx.x * 256 + t;
  int v = 0;
  if (i < n) {
    uint w = degpack[i];
    v = (w & 0xff) + ((w >> 8) & 0xff) + ((w >> 16) & 0xff) + (w >> 24);
  }
  s[t] = v;
  __syncthreads();
  for (int d = 1; d < 256; d <<= 1) {
    int u = (t >= d) ? s[t - d] : 0;
    __syncthreads();
    s[t] += u;
    __syncthreads();
  }
  if (i < n) off[i] = s[t] - v;
  if (t == 255) bsum[blockIdx.x] = s[255];
}

__global__ __launch_bounds__(256) void k_scan2(const int* __restrict__ bsum,
                                               int* __restrict__ bex, int nb) {
  __shared__ int s[256];
  int t = threadIdx.x;
  int v = (t < nb) ? bsum[t] : 0;
  s[t] = v;
  __syncthreads();
  for (int d = 1; d < 256; d <<= 1) {
    int u = (t >= d) ? s[t - d] : 0;
    __syncthreads();
    s[t] += u;
    __syncthreads();
  }
  if (t < nb) bex[t] = s[t] - v;
}

// finalize offsets + cursors + dinv
__global__ __launch_bounds__(256) void k_scan3(int* __restrict__ off,
                                               const int* __restrict__ bex,
                                               const uint* __restrict__ degpack,
                                               int* __restrict__ cursor4,
                                               float* __restrict__ dinv, int n) {
  int i = blockIdx.x * 256 + threadIdx.x;
  if (i >= n) return;
  int o = off[i] + bex[blockIdx.x];
  off[i] = o;
  uint w = degpack[i];
  int b0 = w & 0xff, b1 = (w >> 8) & 0xff, b2 = (w >> 16) & 0xff, b3 = w >> 24;
  int4 c;
  c.x = o;
  c.y = o + b0;
  c.z = o + b0 + b1;
  c.w = o + b0 + b1 + b2;
  *(int4*)&cursor4[i * 4] = c;
  float4 dv;
  dv.x = rsqrtf((float)b0 + 1.0f);
  dv.y = rsqrtf((float)b1 + 1.0f);
  dv.z = rsqrtf((float)b2 + 1.0f);
  dv.w = rsqrtf((float)b3 + 1.0f);
  *(float4*)&dinv[i * 4] = dv;
}

// ---------------- GEMM body (shared by k_gemm and the fused kernel) ----------------
__device__ __forceinline__ void gemm_body(const uint* __restrict__ Xhi,
                                          const short* __restrict__ Whi,
                                          const short* __restrict__ Wlo,
                                          ushort* __restrict__ Hb16,
                                          int N, int bid, short* xs_hi) {
  int t = threadIdx.x;
  int r0 = bid * 64;

  {
    int fi = t * 2;                  // 1024 half-loads done as 512 x 2
    int row = fi >> 4;
    int kq = fi & 15;
    int rg = r0 + row;
    if (rg >= N) rg = N - 1;
    int swz0 = kq ^ (row & 7);
    int swz1 = (kq + 1) ^ (row & 7);
    *(uint4*)&xs_hi[row * 128 + swz0 * 8] = *(const uint4*)&Xhi[(size_t)rg * 64 + kq * 4];
    *(uint4*)&xs_hi[row * 128 + swz1 * 8] = *(const uint4*)&Xhi[(size_t)rg * 64 + (kq + 1) * 4];
  }
  __syncthreads();

  int wid = t >> 6, lane = t & 63;
  int wrow = wid & 1, wcol = wid >> 1;   // 2 x 4 waves
  int lr = lane & 15, lk = lane >> 4;

  f32x4 acc[2][2];
#pragma unroll
  for (int a = 0; a < 2; ++a)
#pragma unroll
    for (int c = 0; c < 2; ++c) acc[a][c] = (f32x4){0.f, 0.f, 0.f, 0.f};

#pragma unroll
  for (int ks = 0; ks < 4; ++ks) {
    int k0 = ks * 32 + lk * 8;
    short8v ah[2];
#pragma unroll
    for (int rt = 0; rt < 2; ++rt) {
      int r = wrow * 32 + rt * 16 + lr;
      int slot = (k0 >> 3) ^ (r & 7);
      ah[rt] = *(short8v*)&xs_hi[r * 128 + slot * 8];
    }
    short8v bh[2], bl[2];
#pragma unroll
    for (int ct = 0; ct < 2; ++ct) {
      int col = wcol * 32 + ct * 16 + lr;
      bh[ct] = *(const short8v*)&Whi[(size_t)col * 128 + k0];
      bl[ct] = *(const short8v*)&Wlo[(size_t)col * 128 + k0];
    }
#pragma unroll
    for (int rt = 0; rt < 2; ++rt)
#pragma unroll
      for (int ct = 0; ct < 2; ++ct) {
        acc[rt][ct] = __builtin_amdgcn_mfma_f32_16x16x32_bf16(ah[rt], bh[ct], acc[rt][ct], 0, 0, 0);
        acc[rt][ct] = __builtin_amdgcn_mfma_f32_16x16x32_bf16(ah[rt], bl[ct], acc[rt][ct], 0, 0, 0);
      }
  }

#pragma unroll
  for (int rt = 0; rt < 2; ++rt)
#pragma unroll
    for (int ct = 0; ct < 2; ++ct) {
      int col = wcol * 32 + ct * 16 + lr;
#pragma unroll
      for (int i = 0; i < 4; ++i) {
        int row = r0 + wrow * 32 + rt * 16 + lk * 4 + i;
        if (row < N) Hb16[(size_t)row * 128 + col] = (ushort)f2bf(acc[rt][ct][i]);
      }
    }
}

// ---------------- standalone GEMM (layers 1..L-1) ----------------
__global__ __launch_bounds__(512) void k_gemm(const uint* __restrict__ Xhi,
                                              const short* __restrict__ Whi,
                                              const short* __restrict__ Wlo,
                                              ushort* __restrict__ Hb16, int N) {
  __shared__ __align__(16) short xs_hi[64 * 128];
  gemm_body(Xhi, Whi, Wlo, Hb16, N, blockIdx.x, xs_hi);
}

// ---------------- fused: scatter + layer-0 GEMM (horizontal fusion) ----------------
// blocks [0, nbg): GEMM tiles; blocks [nbg, ...): edge scatter (512 threads each)
__global__ __launch_bounds__(512) void k_scatter_gemm(
    const int* __restrict__ ei, const int* __restrict__ attr,
    const float* __restrict__ dinv, int* __restrict__ cursor4,
    uint* __restrict__ srcnm, int E,
    const uint* __restrict__ Xhi, const short* __restrict__ Whi,
    const short* __restrict__ Wlo, ushort* __restrict__ Hb16,
    int N, int nbg) {
  __shared__ __align__(16) short xs_hi[64 * 128];
  int bid = blockIdx.x;
  if (bid < nbg) {
    gemm_body(Xhi, Whi, Wlo, Hb16, N, bid, xs_hi);
    return;
  }
  int e = (bid - nbg) * 512 + threadIdx.x;
  if (e >= E) return;
  int src = ei[e];
  int dst = ei[E + e];
  int k = attr[e] - 1;
  float nm = dinv[src * KH + k] * dinv[dst * KH + k];
  ushort h = __half_as_ushort(__float2half(nm));
  int pos = atomicAdd(&cursor4[dst * KH + k], 1);
  srcnm[pos] = (uint)src | ((uint)h << 16);
}

// ---------------- aggregate + self-loop + bias + residual ReLU + L2 norm ----------------
__global__ __launch_bounds__(256) void k_agg(const int* __restrict__ off,
                                             const uint* __restrict__ degpack,
                                             const uint* __restrict__ srcnm,
                                             const float* __restrict__ dinv,
                                             const uint* __restrict__ Hb,
                                             const float* __restrict__ bias,
                                             const float* __restrict__ alpha,
                                             uint* __restrict__ Xhi,
                                             uint* __restrict__ Xlo,
                                             float2* __restrict__ Xout,
                                             int last, int N) {
  int wid = threadIdx.x >> 6;
  int lane = threadIdx.x & 63;
  int n = blockIdx.x * 4 + wid;
  if (n >= N) return;

  int g = lane >> 4;       // edge group 0..3
  int cl = lane & 15;      // uint4 slot within row
  int q = cl * 4 + g;      // lane's owned uint column (bijection)

  // hoisted epilogue loads
  uint un = Hb[(size_t)n * 64 + q];
  float2 bb = ((const float2*)bias)[q];
  uint xh = Xhi[(size_t)n * 64 + q];
  uint xl = Xlo[(size_t)n * 64 + q];
  float4 dv = *(const float4*)&dinv[n * 4];

  float a0 = alpha[0], a1 = alpha[1], a2 = alpha[2], a3 = alpha[3];
  float m = fmaxf(fmaxf(a0, a1), fmaxf(a2, a3));
  a0 = __expf(a0 - m); a1 = __expf(a1 - m); a2 = __expf(a2 - m); a3 = __expf(a3 - m);
  float is = 1.0f / (a0 + a1 + a2 + a3);
  a0 *= is; a1 *= is; a2 *= is; a3 *= is;

  uint w = degpack[n];
  int b0 = w & 0xff, b1 = (w >> 8) & 0xff, b2 = (w >> 16) & 0xff, b3 = (int)(w >> 24);
  int e0 = off[n];
  int e1 = e0 + b0 + b1 + b2 + b3;
  int k1 = e0 + b0, k2 = k1 + b1, k3 = k2 + b2;

  const uint4* Hb4 = (const uint4*)Hb;

  float ax0 = 0.f, ax1 = 0.f, ax2 = 0.f, ax3 = 0.f;
  float ay0 = 0.f, ay1 = 0.f, ay2 = 0.f, ay3 = 0.f;

  for (int base = e0; base < e1; base += 64) {
    int cnt = min(64, e1 - base);
    int sofs = 0;        // src * 16 (uint4 row offset)
    float wc = 0.f;
    if (lane < cnt) {
      uint v = srcnm[base + lane];
      int pos = base + lane;
      int k = (pos >= k1) + (pos >= k2) + (pos >= k3);
      float ak = (k == 0) ? a0 : (k == 1) ? a1 : (k == 2) ? a2 : a3;
      wc = ak * __half2float(__ushort_as_half((ushort)(v >> 16)));
      sofs = (int)(v & 0xFFFFu) << 4;
    }
    int j = 0;
    for (; j + 8 <= cnt; j += 8) {
      int i0 = j + g, i1 = j + 4 + g;
      int s0 = __shfl(sofs, i0);
      int s1 = __shfl(sofs, i1);
      float w0 = __shfl(wc, i0);
      float w1 = __shfl(wc, i1);
      uint4 u0 = Hb4[s0 + cl];
      uint4 u1 = Hb4[s1 + cl];
      ax0 = fmaf(w0, bflo(u0.x), ax0); ay0 = fmaf(w0, bfhi(u0.x), ay0);
      ax1 = fmaf(w0, bflo(u0.y), ax1); ay1 = fmaf(w0, bfhi(u0.y), ay1);
      ax2 = fmaf(w0, bflo(u0.z), ax2); ay2 = fmaf(w0, bfhi(u0.z), ay2);
      ax3 = fmaf(w0, bflo(u0.w), ax3); ay3 = fmaf(w0, bfhi(u0.w), ay3);
      ax0 = fmaf(w1, bflo(u1.x), ax0); ay0 = fmaf(w1, bfhi(u1.x), ay0);
      ax1 = fmaf(w1, bflo(u1.y), ax1); ay1 = fmaf(w1, bfhi(u1.y), ay1);
      ax2 = fmaf(w1, bflo(u1.z), ax2); ay2 = fmaf(w1, bfhi(u1.z), ay2);
      ax3 = fmaf(w1, bflo(u1.w), ax3); ay3 = fmaf(w1, bfhi(u1.w), ay3);
    }
    for (; j < cnt; j += 4) {
      int i0 = j + g;                      // lanes past cnt carry wc=0
      int s0 = __shfl(sofs, i0);
      float w0 = __shfl(wc, i0);
      uint4 u0 = Hb4[s0 + cl];
      ax0 = fmaf(w0, bflo(u0.x), ax0); ay0 = fmaf(w0, bfhi(u0.x), ay0);
      ax1 = fmaf(w0, bflo(u0.y), ax1); ay1 = fmaf(w0, bfhi(u0.y), ay1);
      ax2 = fmaf(w0, bflo(u0.z), ax2); ay2 = fmaf(w0, bfhi(u0.z), ay2);
      ax3 = fmaf(w0, bflo(u0.w), ax3); ay3 = fmaf(w0, bfhi(u0.w), ay3);
    }
  }

  // reduce across the 4 edge-groups
  ax0 += __shfl_xor(ax0, 16); ax0 += __shfl_xor(ax0, 32);
  ax1 += __shfl_xor(ax1, 16); ax1 += __shfl_xor(ax1, 32);
  ax2 += __shfl_xor(ax2, 16); ax2 += __shfl_xor(ax2, 32);
  ax3 += __shfl_xor(ax3, 16); ax3 += __shfl_xor(ax3, 32);
  ay0 += __shfl_xor(ay0, 16); ay0 += __shfl_xor(ay0, 32);
  ay1 += __shfl_xor(ay1, 16); ay1 += __shfl_xor(ay1, 32);
  ay2 += __shfl_xor(ay2, 16); ay2 += __shfl_xor(ay2, 32);
  ay3 += __shfl_xor(ay3, 16); ay3 += __shfl_xor(ay3, 32);

  float accx = (g == 0) ? ax0 : (g == 1) ? ax1 : (g == 2) ? ax2 : ax3;
  float accy = (g == 0) ? ay0 : (g == 1) ? ay1 : (g == 2) ? ay2 : ay3;

  float sc = a0 * dv.x * dv.x + a1 * dv.y * dv.y + a2 * dv.z * dv.z + a3 * dv.w * dv.w;

  float xr0 = bf2f(xh) + bf2f(xl);                  // ~fp32 residual base
  float xr1 = bfhi(xh) + bfhi(xl);
  float o0 = accx + sc * bflo(un) + bb.x;
  float o1 = accy + sc * bfhi(un) + bb.y;
  float x0 = xr0 + fmaxf(o0, 0.f);
  float x1 = xr1 + fmaxf(o1, 0.f);

  float ss = x0 * x0 + x1 * x1;
#pragma unroll
  for (int d = 32; d; d >>= 1) ss += __shfl_xor(ss, d);
  float nrm = fmaxf(sqrtf(ss), 1e-12f);
  float inv = 1.0f / nrm;
  float y0 = x0 * inv, y1 = x1 * inv;

  uint h0 = f2bf(y0), h1 = f2bf(y1);
  Xhi[(size_t)n * 64 + q] = h0 | (h1 << 16);
  uint l0 = f2bf(y0 - bf2f(h0)), l1 = f2bf(y1 - bf2f(h1));
  Xlo[(size_t)n * 64 + q] = l0 | (l1 << 16);
  if (last) Xout[(size_t)n * 64 + q] = make_float2(y0, y1);
}

// ---------------- host launcher ----------------
extern "C" void kernel_launch(void* const* d_in, const int* in_sizes, int n_in,
                              void* d_out, int out_size, void* d_ws, size_t ws_size,
                              hipStream_t stream) {
  const float* x = (const float*)d_in[0];
  const int* ei = (const int*)d_in[1];
  const int* attr = (const int*)d_in[2];
  const float* W = (const float*)d_in[3];
  const float* b = (const float*)d_in[4];
  const float* alpha = (const float*)d_in[5];
  float* X = (float*)d_out;

  int N = in_sizes[0] / DIM;
  int E = in_sizes[1] / 2;
  int L = in_sizes[3] / (DIM * DIM);

  char* base = (char*)d_ws;
  size_t ofs = 0;
  auto carve = [&](size_t bytes) -> void* {
    void* p = base + ofs;
    ofs = (ofs + bytes + 255) & ~(size_t)255;
    return p;
  };
  int* off = (int*)carve((size_t)(N + 1) * 4);
  int* cursor4 = (int*)carve((size_t)N * KH * 4);
  uint* degpack = (uint*)carve((size_t)N * 4);
  float* dinv = (float*)carve((size_t)N * KH * 4);
  int* bsum = (int*)carve(256 * 4);
  int* bex = (int*)carve(256 * 4);
  uint* srcnm = (uint*)carve((size_t)E * 4);
  uint* Hb = (uint*)carve((size_t)N * 64 * 4);
  uint* Xhi = (uint*)carve((size_t)N * 64 * 4);
  uint* Xlo = (uint*)carve((size_t)N * 64 * 4);
  short* Whi = (short*)carve((size_t)L * DIM * DIM * 2);
  short* Wlo = (short*)carve((size_t)L * DIM * DIM * 2);

  int n4 = N * DIM / 4;
  int nb = (N + 255) / 256;
  int wtot = L * DIM * DIM;
  int imax = (n4 > E) ? n4 : E;
  if (wtot > imax) imax = wtot;
  int nbg = (N + 63) / 64;
  int nbs = (E + 511) / 512;

  k_zero<<<(N + 255) / 256, 256, 0, stream>>>(degpack, N);
  k_init_count<<<(imax + 255) / 256, 256, 0, stream>>>((const float4*)x, Xhi, Xlo,
                                                       ei, attr, degpack,
                                                       W, Whi, Wlo, n4, E, wtot);
  k_scan1<<<nb, 256, 0, stream>>>(degpack, off, bsum, N);
  k_scan2<<<1, 256, 0, stream>>>(bsum, bex, nb);
  k_scan3<<<nb, 256, 0, stream>>>(off, bex, degpack, cursor4, dinv, N);
  // fused: edge scatter + layer-0 GEMM
  k_scatter_gemm<<<nbg + nbs, 512, 0, stream>>>(ei, attr, dinv, cursor4, srcnm, E,
                                                Xhi, Whi, Wlo, (ushort*)Hb, N, nbg);

  for (int t = 0; t < L; ++t) {
    if (t > 0)
      k_gemm<<<nbg, 512, 0, stream>>>(Xhi,
                                      Whi + (size_t)t * DIM * DIM,
                                      Wlo + (size_t)t * DIM * DIM,
                                      (ushort*)Hb, N);
    k_agg<<<(N + 3) / 4, 256, 0, stream>>>(off, degpack, srcnm, dinv, Hb,
                                           b + (size_t)t * DIM, alpha + (size_t)t * KH,
                                           Xhi, Xlo, (float2*)X,
                                           (t == L - 1) ? 1 : 0, N);
  }
}